// Round 14
// baseline (46838.861 us; speedup 1.0000x reference)
//
#include <hip/hip_runtime.h>

#define HID   1024
#define SEQT  8192
#define NBLK  256
#define TPB   512   // 8 waves: widx 0-3 = L1 rows+h1-poll, widx 4-7 = L2 rows+h2-poll

// ws (bytes): [0,16K) u64 h1t[2][1024] ; [16K,32K) u64 h2t[2][1024]
// packed slot: (tag<<32)|fp32_bits ; h(s) in slot s&1 with tag s+1; init 0
#define WS_BYTES 32768

typedef float v16f __attribute__((ext_vector_type(16)));
typedef unsigned long long u64;

__device__ __forceinline__ float sig_(float x) { return 1.0f / (1.0f + expf(-x)); }

__device__ __forceinline__ u64 ldp(const u64* p) {
    return __hip_atomic_load(p, __ATOMIC_RELAXED, __HIP_MEMORY_SCOPE_AGENT);
}
__device__ __forceinline__ void stp(u64* p, u64 v) {
    __hip_atomic_store(p, v, __ATOMIC_RELAXED, __HIP_MEMORY_SCOPE_AGENT);
}

extern "C" __global__ void __launch_bounds__(TPB, 2)
lstm_split(const float* __restrict__ seq,
           const float* __restrict__ w_ih1, const float* __restrict__ w_hh1,
           const float* __restrict__ b_ih1, const float* __restrict__ b_hh1,
           const float* __restrict__ w_ih2, const float* __restrict__ w_hh2,
           const float* __restrict__ b_ih2, const float* __restrict__ b_hh2,
           const float* __restrict__ w_lin, const float* __restrict__ b_lin,
           float* __restrict__ out, u64* ws)
{
    __shared__ float h1s[2][HID];   // staged h1, dbuf by t&1   8 KB
    __shared__ float h2s[2][HID];   // staged h2, dbuf by t&1   8 KB
    __shared__ float seqs[SEQT];    // input sequence          32 KB

    const int  lane = threadIdx.x & 63;
    const int  widx = threadIdx.x >> 6;        // 0..7
    const int  blk  = blockIdx.x;
    const bool isL1 = (widx < 4);
    const int  r    = blk * 4 + (widx & 3);    // owned hidden row

    u64* h1t = ws;            // [2][1024]
    u64* h2t = ws + 2048;     // [2][1024]

    for (int i = threadIdx.x; i < SEQT; i += TPB) seqs[i] = seq[i];

    // ---- stationary weights, BRANCH-FREE (r9 champion config: compiler
    // streams them from L1/L2; proven to overlap with the sync chain) ----
    const float* bA  = isL1 ? w_hh1 : w_ih2;
    const float* bB  = isL1 ? w_hh1 : w_hh2;   // L1: B-dot zeroed via zmask
    const float* bbi = isL1 ? b_ih1 : b_ih2;
    const float* bbh = isL1 ? b_hh1 : b_hh2;
    const float  zmask = isL1 ? 0.f : 1.f;
    const float  xsel  = isL1 ? 1.f : 0.f;

    v16f A0, A1, A2, A3, B0, B1, B2, B3;
    {
        const size_t ro = (size_t)r * HID + lane;
        const float *a0 = bA + ro, *a1 = bA + (size_t)HID * HID + ro,
                    *a2 = bA + 2 * (size_t)HID * HID + ro, *a3 = bA + 3 * (size_t)HID * HID + ro;
        const float *b0 = bB + ro, *b1 = bB + (size_t)HID * HID + ro,
                    *b2 = bB + 2 * (size_t)HID * HID + ro, *b3 = bB + 3 * (size_t)HID * HID + ro;
#pragma unroll
        for (int k = 0; k < 16; ++k) {
            A0[k] = a0[64 * k]; A1[k] = a1[64 * k]; A2[k] = a2[64 * k]; A3[k] = a3[64 * k];
            B0[k] = b0[64 * k]; B1[k] = b1[64 * k]; B2[k] = b2[64 * k]; B3[k] = b3[64 * k];
        }
    }
    const float wx0 = w_ih1[0 * HID + r], wx1 = w_ih1[1 * HID + r],
                wx2 = w_ih1[2 * HID + r], wx3 = w_ih1[3 * HID + r];
    const float bb0 = bbi[0 * HID + r] + bbh[0 * HID + r];
    const float bb1 = bbi[1 * HID + r] + bbh[1 * HID + r];
    const float bb2 = bbi[2 * HID + r] + bbh[2 * HID + r];
    const float bb3 = bbi[3 * HID + r] + bbh[3 * HID + r];

    const bool carrier = (blk == 0 && widx == 7);   // an L2 wave
    v16f WL; float blin = 0.f;
#pragma unroll
    for (int k = 0; k < 16; ++k) WL[k] = 0.f;
    if (carrier) {
#pragma unroll
        for (int k = 0; k < 16; ++k) WL[k] = w_lin[lane + 64 * k];
        blin = b_lin[0];
    }

    u64* pub = isL1 ? h1t : h2t;
    float c = 0.f;

    // Lock-step schedule, ONE barrier/step (r9 skeleton + 8-way poll split):
    //   t: L1 -> h1(t) [t<SEQT]; L2 -> h2(t-1) [1<=t<=SEQT]; OUT -> out(t-2) [t>=2]
    // Poll split: wave w<4 polls h1 slots [w*256, w*256+256) (4 loads/lane);
    // wave w>=4 polls h2 slots [(w-4)*256, ...). Spin iteration = 4-load RTT
    // (was 16) -> ~4x finer detection granularity; staging is in-loop (r9
    // style: already written when detection succeeds) and 8-way parallel.
    // Overwrite safety: unchanged hb-chain (publish(t) <= this block saw
    // h2(t-2) full <= all blocks' step-(t-1) polls completed). LDS dbuf
    // safety: buffer t&1 is re-written at t+2 only after this wave passed
    // barrier(t+1), which requires all waves finished compute(t).
    for (int t = 0; t <= SEQT + 1; ++t) {
        const int cur = t & 1;

        if (isL1) {
            if (t <= SEQT) {
                // poll h1(t-1): slot (t+1)&1, tag >= t (t=0: init tag 0 passes)
                const int base = widx * 256 + lane;
                const u64* p = h1t + ((t + 1) & 1) * HID + base;
                float* dst = &h1s[cur][base];
                int guard = 0;
                for (;;) {
                    u64 q0 = ldp(p);       u64 q1 = ldp(p + 64);
                    u64 q2 = ldp(p + 128); u64 q3 = ldp(p + 192);
                    dst[0]   = __uint_as_float((unsigned)q0);
                    dst[64]  = __uint_as_float((unsigned)q1);
                    dst[128] = __uint_as_float((unsigned)q2);
                    dst[192] = __uint_as_float((unsigned)q3);
                    int mn = min(min((int)(q0 >> 32), (int)(q1 >> 32)),
                                 min((int)(q2 >> 32), (int)(q3 >> 32)));
                    if (__all(mn >= t)) break;
                    if (++guard > (1 << 13)) break;   // bounded failsafe
                }
            }
        } else {
            // poll h2(t-2): slot t&1, tag >= t-1 (t<=1: init tag 0 passes)
            const int base = (widx - 4) * 256 + lane;
            const u64* p = h2t + cur * HID + base;
            float* dst = &h2s[cur][base];
            const int thr = t - 1;
            int guard = 0;
            for (;;) {
                u64 q0 = ldp(p);       u64 q1 = ldp(p + 64);
                u64 q2 = ldp(p + 128); u64 q3 = ldp(p + 192);
                dst[0]   = __uint_as_float((unsigned)q0);
                dst[64]  = __uint_as_float((unsigned)q1);
                dst[128] = __uint_as_float((unsigned)q2);
                dst[192] = __uint_as_float((unsigned)q3);
                int mn = min(min((int)(q0 >> 32), (int)(q1 >> 32)),
                             min((int)(q2 >> 32), (int)(q3 >> 32)));
                if (__all(mn >= thr)) break;
                if (++guard > (1 << 13)) break;
            }
        }
        __syncthreads();

        const bool act = isL1 ? (t < SEQT) : (t >= 1 && t <= SEQT);
        if (act) {
            v16f v1, v2;
#pragma unroll
            for (int k = 0; k < 16; ++k) {
                v1[k] = h1s[cur][lane + 64 * k];
                v2[k] = h2s[cur][lane + 64 * k] * zmask;
            }
            float a0 = 0.f, a1 = 0.f, a2 = 0.f, a3 = 0.f;
#pragma unroll
            for (int k = 0; k < 16; ++k) {
                a0 = fmaf(A0[k], v1[k], a0);
                a1 = fmaf(A1[k], v1[k], a1);
                a2 = fmaf(A2[k], v1[k], a2);
                a3 = fmaf(A3[k], v1[k], a3);
            }
#pragma unroll
            for (int k = 0; k < 16; ++k) {
                a0 = fmaf(B0[k], v2[k], a0);
                a1 = fmaf(B1[k], v2[k], a1);
                a2 = fmaf(B2[k], v2[k], a2);
                a3 = fmaf(B3[k], v2[k], a3);
            }
#pragma unroll
            for (int s = 32; s; s >>= 1) {
                a0 += __shfl_xor(a0, s);
                a1 += __shfl_xor(a1, s);
                a2 += __shfl_xor(a2, s);
                a3 += __shfl_xor(a3, s);
            }
            const float xg = xsel * ((t < SEQT) ? seqs[t] : 0.f);
            float i_ = sig_(a0 + xg * wx0 + bb0);
            float f_ = sig_(a1 + xg * wx1 + bb1);
            float g_ = tanhf(a2 + xg * wx2 + bb2);
            float o_ = sig_(a3 + xg * wx3 + bb3);
            c = f_ * c + i_ * g_;
            float h = o_ * tanhf(c);
            if (lane == 0) {
                const int ps = isL1 ? t : (t - 1);   // produced timestep
                stp(pub + (ps & 1) * HID + r,
                    ((u64)(unsigned)(ps + 1) << 32) | (u64)__float_as_uint(h));
            }
        }

        // out(t-2) from staged h2s[cur] (full vector, staged by waves 4-7)
        if (carrier && t >= 2) {
            float ov = 0.f;
#pragma unroll
            for (int k = 0; k < 16; ++k) ov = fmaf(WL[k], h2s[cur][lane + 64 * k], ov);
#pragma unroll
            for (int s = 32; s; s >>= 1) ov += __shfl_xor(ov, s);
            if (lane == 0) out[t - 2] = ov + blin;
        }
    }
}

extern "C" void kernel_launch(void* const* d_in, const int* in_sizes, int n_in,
                              void* d_out, int out_size, void* d_ws, size_t ws_size,
                              hipStream_t stream)
{
    (void)hipMemsetAsync(d_ws, 0, WS_BYTES, stream);

    const float* seq  = (const float*)d_in[0];
    const float* wih1 = (const float*)d_in[1];
    const float* whh1 = (const float*)d_in[2];
    const float* bih1 = (const float*)d_in[3];
    const float* bhh1 = (const float*)d_in[4];
    const float* wih2 = (const float*)d_in[5];
    const float* whh2 = (const float*)d_in[6];
    const float* bih2 = (const float*)d_in[7];
    const float* bhh2 = (const float*)d_in[8];
    const float* wlin = (const float*)d_in[9];
    const float* blin = (const float*)d_in[10];
    float* out = (float*)d_out;
    u64*   ws  = (u64*)d_ws;

    hipLaunchKernelGGL(lstm_split, dim3(NBLK), dim3(TPB), 0, stream,
                       seq, wih1, whh1, bih1, bhh1,
                       wih2, whh2, bih2, bhh2, wlin, blin,
                       out, ws);
}

// Round 15
// 29657.315 us; speedup vs baseline: 1.5793x; 1.5793x over previous
//
#include <hip/hip_runtime.h>

#define HID   1024
#define SEQT  8192
#define NBLK  256
#define TPB   512   // 8 waves: widx 0-3 = L1 rows, widx 4-7 = L2 rows

// ws (bytes): [0,16K) u64 h1t[2][1024] ; [16K,32K) u64 h2t[2][1024]
// packed slot: (tag<<32)|fp32_bits ; h(s) in slot s&1 with tag s+1; init 0
#define WS_BYTES 32768

typedef float v16f __attribute__((ext_vector_type(16)));
typedef _Float16 f16x8 __attribute__((ext_vector_type(8)));
typedef unsigned long long u64;

__device__ __forceinline__ float sig_(float x) { return 1.0f / (1.0f + expf(-x)); }

__device__ __forceinline__ u64 ldp(const u64* p) {
    return __hip_atomic_load(p, __ATOMIC_RELAXED, __HIP_MEMORY_SCOPE_AGENT);
}
__device__ __forceinline__ void stp(u64* p, u64 v) {
    __hip_atomic_store(p, v, __ATOMIC_RELAXED, __HIP_MEMORY_SCOPE_AGENT);
}

extern "C" __global__ void __launch_bounds__(TPB, 2)
lstm_w16(const float* __restrict__ seq,
         const float* __restrict__ w_ih1, const float* __restrict__ w_hh1,
         const float* __restrict__ b_ih1, const float* __restrict__ b_hh1,
         const float* __restrict__ w_ih2, const float* __restrict__ w_hh2,
         const float* __restrict__ b_ih2, const float* __restrict__ b_hh2,
         const float* __restrict__ w_lin, const float* __restrict__ b_lin,
         float* __restrict__ out, u64* ws)
{
    // f16 weights in LDS: wA[wave][j][lane] = {g0lo,g0hi,g1lo,g1hi,...} for
    // column pair (lane+128j, lane+128j+64) -> one ds_read_b128 per j.
    __shared__ f16x8 wA[8][8][64];   // L1: w_hh1 | L2: w_ih2   64 KB
    __shared__ f16x8 wB[4][8][64];   // L2: w_hh2               32 KB
    __shared__ float h1s[HID];       // staged h1(t-1)            4 KB
    __shared__ float h2s[HID];       // staged h2(t-2)            4 KB
    __shared__ float seqs[SEQT];     // input sequence           32 KB

    const int  lane = threadIdx.x & 63;
    const int  widx = threadIdx.x >> 6;        // 0..7
    const int  blk  = blockIdx.x;
    const bool isL1 = (widx < 4);
    const int  r    = blk * 4 + (widx & 3);    // owned hidden row

    u64* h1t = ws;            // [2][1024]
    u64* h2t = ws + 2048;     // [2][1024]

    for (int i = threadIdx.x; i < SEQT; i += TPB) seqs[i] = seq[i];

    // ---- one-time weight load -> f16 LDS (each wave fills its own region) ----
    if (isL1) {
#pragma unroll
        for (int j = 0; j < 8; ++j) {
            f16x8 w;
#pragma unroll
            for (int g = 0; g < 4; ++g) {
                const float* row = w_hh1 + (size_t)(g * HID + r) * HID;
                w[2 * g]     = (_Float16)row[lane + 128 * j];
                w[2 * g + 1] = (_Float16)row[lane + 128 * j + 64];
            }
            wA[widx][j][lane] = w;
        }
    } else {
#pragma unroll
        for (int j = 0; j < 8; ++j) {
            f16x8 wi, wh;
#pragma unroll
            for (int g = 0; g < 4; ++g) {
                const float* ri = w_ih2 + (size_t)(g * HID + r) * HID;
                const float* rh = w_hh2 + (size_t)(g * HID + r) * HID;
                wi[2 * g]     = (_Float16)ri[lane + 128 * j];
                wi[2 * g + 1] = (_Float16)ri[lane + 128 * j + 64];
                wh[2 * g]     = (_Float16)rh[lane + 128 * j];
                wh[2 * g + 1] = (_Float16)rh[lane + 128 * j + 64];
            }
            wA[widx][j][lane]     = wi;
            wB[widx - 4][j][lane] = wh;
        }
    }
    // branch-free body: L1's "B" pointer aliases its own wA (zmask kills it)
    const f16x8* wAp = &wA[widx][0][0];                         // [8][64] flat
    const f16x8* wBp = isL1 ? wAp : &wB[widx - 4][0][0];
    const float  zmask = isL1 ? 0.f : 1.f;
    const float  xsel  = isL1 ? 1.f : 0.f;

    const float* bbi = isL1 ? b_ih1 : b_ih2;
    const float* bbh = isL1 ? b_hh1 : b_hh2;
    const float wx0 = w_ih1[0 * HID + r], wx1 = w_ih1[1 * HID + r],
                wx2 = w_ih1[2 * HID + r], wx3 = w_ih1[3 * HID + r];
    const float bb0 = bbi[0 * HID + r] + bbh[0 * HID + r];
    const float bb1 = bbi[1 * HID + r] + bbh[1 * HID + r];
    const float bb2 = bbi[2 * HID + r] + bbh[2 * HID + r];
    const float bb3 = bbi[3 * HID + r] + bbh[3 * HID + r];

    const bool carrier = (blk == 0 && widx == 7);   // an L2 wave
    v16f WL; float blin = 0.f;
#pragma unroll
    for (int k = 0; k < 16; ++k) WL[k] = 0.f;
    if (carrier) {
#pragma unroll
        for (int k = 0; k < 16; ++k) WL[k] = w_lin[lane + 64 * k];
        blin = b_lin[0];
    }

    u64* pub = isL1 ? h1t : h2t;
    float c = 0.f;

    // Round-9 champion skeleton (2 barriers/step, in-spin LDS staging):
    //   t: L1 -> h1(t) [t<SEQT]; L2 -> h2(t-1) [1<=t<=SEQT]; OUT -> out(t-2) [t>=2]
    // Overwrite safety: publish(t) <= this block saw h2(t-2) full <= all
    // blocks' step-(t-1) polls completed -> no readers of clobbered slots.
    for (int t = 0; t <= SEQT + 1; ++t) {
        if (widx == 0 && t <= SEQT) {
            // poll h1(t-1): slot (t+1)&1, tag >= t (t=0: init tag 0 passes)
            const u64* p = h1t + ((t + 1) & 1) * HID + lane;
            int guard = 0;
            for (;;) {
                int mn = 0x7fffffff;
                u64 q[16];
#pragma unroll
                for (int k = 0; k < 16; ++k) {
                    q[k] = ldp(p + 64 * k);
                    mn = min(mn, (int)(q[k] >> 32));
                }
#pragma unroll
                for (int k = 0; k < 16; ++k)
                    h1s[lane + 64 * k] = __uint_as_float((unsigned)q[k]);
                if (__all(mn >= t)) break;
                if (++guard > (1 << 14)) break;   // bounded: fail loud, fast
            }
        }
        if (widx == 4) {
            // poll h2(t-2): slot t&1, tag >= t-1 (t<=1: init tag 0 passes)
            const u64* p = h2t + (t & 1) * HID + lane;
            const int thr = t - 1;
            int guard = 0;
            for (;;) {
                int mn = 0x7fffffff;
                u64 q[16];
#pragma unroll
                for (int k = 0; k < 16; ++k) {
                    q[k] = ldp(p + 64 * k);
                    mn = min(mn, (int)(q[k] >> 32));
                }
#pragma unroll
                for (int k = 0; k < 16; ++k)
                    h2s[lane + 64 * k] = __uint_as_float((unsigned)q[k]);
                if (__all(mn >= thr)) break;
                if (++guard > (1 << 14)) break;
            }
        }
        __syncthreads();

        const bool act = isL1 ? (t < SEQT) : (t >= 1 && t <= SEQT);
        if (act) {
            v16f v1, v2;
#pragma unroll
            for (int k = 0; k < 16; ++k) {
                v1[k] = h1s[lane + 64 * k];
                v2[k] = h2s[lane + 64 * k] * zmask;
            }
            float a0 = 0.f, a1 = 0.f, a2 = 0.f, a3 = 0.f;
#pragma unroll
            for (int j = 0; j < 8; ++j) {
                const f16x8 w = wAp[j * 64 + lane];
                a0 = fmaf((float)w[0], v1[2 * j],     a0);
                a0 = fmaf((float)w[1], v1[2 * j + 1], a0);
                a1 = fmaf((float)w[2], v1[2 * j],     a1);
                a1 = fmaf((float)w[3], v1[2 * j + 1], a1);
                a2 = fmaf((float)w[4], v1[2 * j],     a2);
                a2 = fmaf((float)w[5], v1[2 * j + 1], a2);
                a3 = fmaf((float)w[6], v1[2 * j],     a3);
                a3 = fmaf((float)w[7], v1[2 * j + 1], a3);
            }
#pragma unroll
            for (int j = 0; j < 8; ++j) {
                const f16x8 w = wBp[j * 64 + lane];
                a0 = fmaf((float)w[0], v2[2 * j],     a0);
                a0 = fmaf((float)w[1], v2[2 * j + 1], a0);
                a1 = fmaf((float)w[2], v2[2 * j],     a1);
                a1 = fmaf((float)w[3], v2[2 * j + 1], a1);
                a2 = fmaf((float)w[4], v2[2 * j],     a2);
                a2 = fmaf((float)w[5], v2[2 * j + 1], a2);
                a3 = fmaf((float)w[6], v2[2 * j],     a3);
                a3 = fmaf((float)w[7], v2[2 * j + 1], a3);
            }
#pragma unroll
            for (int s = 32; s; s >>= 1) {
                a0 += __shfl_xor(a0, s);
                a1 += __shfl_xor(a1, s);
                a2 += __shfl_xor(a2, s);
                a3 += __shfl_xor(a3, s);
            }
            const float xg = xsel * ((t < SEQT) ? seqs[t] : 0.f);
            float i_ = sig_(a0 + xg * wx0 + bb0);
            float f_ = sig_(a1 + xg * wx1 + bb1);
            float g_ = tanhf(a2 + xg * wx2 + bb2);
            float o_ = sig_(a3 + xg * wx3 + bb3);
            c = f_ * c + i_ * g_;
            float h = o_ * tanhf(c);
            if (lane == 0) {
                const int ps = isL1 ? t : (t - 1);   // produced timestep
                stp(pub + (ps & 1) * HID + r,
                    ((u64)(unsigned)(ps + 1) << 32) | (u64)__float_as_uint(h));
            }
        }

        // out(t-2) from staged h2s (f32, exact)
        if (carrier && t >= 2) {
            float ov = 0.f;
#pragma unroll
            for (int k = 0; k < 16; ++k) ov = fmaf(WL[k], h2s[lane + 64 * k], ov);
#pragma unroll
            for (int s = 32; s; s >>= 1) ov += __shfl_xor(ov, s);
            if (lane == 0) out[t - 2] = ov + blin;
        }

        __syncthreads();   // protect LDS from next step's restaging
    }
}

extern "C" void kernel_launch(void* const* d_in, const int* in_sizes, int n_in,
                              void* d_out, int out_size, void* d_ws, size_t ws_size,
                              hipStream_t stream)
{
    (void)hipMemsetAsync(d_ws, 0, WS_BYTES, stream);

    const float* seq  = (const float*)d_in[0];
    const float* wih1 = (const float*)d_in[1];
    const float* whh1 = (const float*)d_in[2];
    const float* bih1 = (const float*)d_in[3];
    const float* bhh1 = (const float*)d_in[4];
    const float* wih2 = (const float*)d_in[5];
    const float* whh2 = (const float*)d_in[6];
    const float* bih2 = (const float*)d_in[7];
    const float* bhh2 = (const float*)d_in[8];
    const float* wlin = (const float*)d_in[9];
    const float* blin = (const float*)d_in[10];
    float* out = (float*)d_out;
    u64*   ws  = (u64*)d_ws;

    hipLaunchKernelGGL(lstm_w16, dim3(NBLK), dim3(TPB), 0, stream,
                       seq, wih1, whh1, bih1, bhh1,
                       wih2, whh2, bih2, bhh2, wlin, blin,
                       out, ws);
}